// Round 7
// baseline (279.980 us; speedup 1.0000x reference)
//
#include <hip/hip_runtime.h>

#define N_GENOMES 4000
#define N_SAMPLES 2048
#define N_GENES   28000
#define N_SEQS    16000
#define MAXW      16     // max genes per seq; P(exceed) ~1e-7 for Poisson(1.75) x 16000
#define NBINS     (N_GENOMES + 1)   // +1 bin for empty seq rows

// ---------------- ELL build (hist of slot-0 genomes fused in) ----------------

__global__ void ell_scatter_k(const int* __restrict__ seq_idx,
                              const int* __restrict__ genome_idx,
                              const float* __restrict__ pos,
                              int* __restrict__ counts,
                              int* __restrict__ bins,
                              int2* __restrict__ ell2) {
    int g = blockIdx.x * blockDim.x + threadIdx.x;
    if (g < N_GENES) {
        int q  = seq_idx[g];
        int gi = genome_idx[g];
        int slot = atomicAdd(&counts[q], 1);
        if (slot < MAXW)
            ell2[q * MAXW + slot] = make_int2(gi, __float_as_int(pos[g]));
        if (slot == 0)
            atomicAdd(&bins[gi], 1);   // histogram of sort keys (slot-0 genome per q)
    }
}

// ---- fused: scan bins (LDS cursors) + build XCD-swizzled permutation ----
// One block. Empty seqs implicitly take positions [T,16000) via cursor[4000]=T.

__global__ __launch_bounds__(1024) void scan_perm_k(const int* __restrict__ bins,
                                                    const int* __restrict__ counts,
                                                    const int2* __restrict__ ell2,
                                                    int* __restrict__ perm) {
    __shared__ int cursor[NBINS];          // 16 KB
    __shared__ int wave_tot[16];
    __shared__ int carry_s;
    const int tid  = threadIdx.x;
    const int lane = tid & 63, wid = tid >> 6;
    if (tid == 0) carry_s = 0;
    __syncthreads();

    for (int base = 0; base < NBINS; base += 1024) {
        const int i   = base + tid;
        const int val = (i < NBINS) ? bins[i] : 0;
        int x = val;                        // inclusive wave scan
#pragma unroll
        for (int off = 1; off < 64; off <<= 1) {
            int y = __shfl_up(x, off, 64);
            if (lane >= off) x += y;
        }
        if (lane == 63) wave_tot[wid] = x;
        __syncthreads();
        if (wid == 0 && lane < 16) {
            int t = wave_tot[lane];
#pragma unroll
            for (int off = 1; off < 16; off <<= 1) {
                int y = __shfl_up(t, off, 64);
                if (lane >= off) t += y;
            }
            wave_tot[lane] = t;             // inclusive wave totals
        }
        __syncthreads();
        const int wbase = (wid == 0) ? 0 : wave_tot[wid - 1];
        const int excl  = x - val + wbase + carry_s;
        if (i < NBINS) cursor[i] = excl;
        __syncthreads();
        if (tid == 0) carry_s += wave_tot[15];   // chunk total
        __syncthreads();
    }

    // scatter: genome-sorted position -> XCD-swizzled block id
    for (int base = 0; base < N_SEQS; base += 1024) {
        const int q = base + tid;
        if (q < N_SEQS) {
            const int cnt = counts[q];
            const int key = (cnt > 0) ? ell2[q * MAXW].x : N_GENOMES;
            const int p = atomicAdd(&cursor[key], 1);
            const int b = (p % 2000) * 8 + (p / 2000);   // XCD = blockIdx % 8
            perm[b] = q;
        }
    }
}

// ---------------- main: one block per output seq row (permuted) ----------------
// out[q, s] = bias[q] * sum_{g : seq_idx[g]==q} A[gi,s] * 2^(1 - pos[g]*B[gi,s])

__global__ __launch_bounds__(256) void main_ell_k(
    const float* __restrict__ A, const float* __restrict__ B,
    const float* __restrict__ bias,
    const int* __restrict__ counts, const int2* __restrict__ ell2,
    const int* __restrict__ perm,
    float* __restrict__ out)
{
    const int q   = perm[blockIdx.x];
    const int tid = threadIdx.x;
    const int s0  = tid * 8;                    // 256 threads * 8 = 2048 samples

    int cnt = counts[q];
    if (cnt > MAXW) cnt = MAXW;
    const int2* row = ell2 + q * MAXW;

    int   gi[MAXW];
    float pp[MAXW];
#pragma unroll
    for (int j = 0; j < MAXW; ++j) {
        const int2 e = row[j];
        gi[j] = e.x;
        pp[j] = __int_as_float(e.y);
    }

    float acc[8];
#pragma unroll
    for (int i = 0; i < 8; ++i) acc[i] = 0.0f;

#pragma unroll
    for (int j = 0; j < MAXW; ++j) {
        if (j < cnt) {
            const float p = pp[j];
            const float4* Ar = (const float4*)(A + (size_t)gi[j] * N_SAMPLES + s0);
            const float4* Br = (const float4*)(B + (size_t)gi[j] * N_SAMPLES + s0);
            const float4 a0 = Ar[0], a1 = Ar[1];
            const float4 b0 = Br[0], b1 = Br[1];
            acc[0] += a0.x * exp2f(1.0f - p * b0.x);
            acc[1] += a0.y * exp2f(1.0f - p * b0.y);
            acc[2] += a0.z * exp2f(1.0f - p * b0.z);
            acc[3] += a0.w * exp2f(1.0f - p * b0.w);
            acc[4] += a1.x * exp2f(1.0f - p * b1.x);
            acc[5] += a1.y * exp2f(1.0f - p * b1.y);
            acc[6] += a1.z * exp2f(1.0f - p * b1.z);
            acc[7] += a1.w * exp2f(1.0f - p * b1.w);
        }
    }

    const float bq = bias[q];
    float4 o0 = make_float4(acc[0] * bq, acc[1] * bq, acc[2] * bq, acc[3] * bq);
    float4 o1 = make_float4(acc[4] * bq, acc[5] * bq, acc[6] * bq, acc[7] * bq);
    float4* Or = (float4*)(out + (size_t)q * N_SAMPLES + s0);
    Or[0] = o0;
    Or[1] = o1;
}

// ---------------- launch ----------------

extern "C" void kernel_launch(void* const* d_in, const int* in_sizes, int n_in,
                              void* d_out, int out_size, void* d_ws, size_t ws_size,
                              hipStream_t stream) {
    const float* A          = (const float*)d_in[0];   // (4000, 2048)
    const float* B          = (const float*)d_in[1];   // (4000, 2048)
    const float* bias       = (const float*)d_in[2];   // (16000,)
    const float* pos        = (const float*)d_in[3];   // (28000,)
    const int*   genome_idx = (const int*)d_in[4];     // (28000,)
    const int*   seq_idx    = (const int*)d_in[5];     // (28000,)
    float*       out        = (float*)d_out;           // (16000, 2048)

    // ws layout (ints): counts[16000] | bins[4001] | pad | ell2[16000*16*2] | perm[16000]
    int*  counts = (int*)d_ws;
    int*  bins   = counts + N_SEQS;
    size_t meta_bytes = (size_t)(N_SEQS + NBINS) * sizeof(int);
    int2* ell2   = (int2*)((char*)d_ws + ((meta_bytes + 15) & ~(size_t)15));
    int*  perm   = (int*)(ell2 + (size_t)N_SEQS * MAXW);

    (void)hipMemsetAsync(counts, 0, meta_bytes, stream);   // zeros counts + bins
    ell_scatter_k<<<(N_GENES + 255) / 256, 256, 0, stream>>>(seq_idx, genome_idx, pos,
                                                             counts, bins, ell2);
    scan_perm_k  <<<1, 1024, 0, stream>>>(bins, counts, ell2, perm);
    main_ell_k   <<<N_SEQS, 256, 0, stream>>>(A, B, bias, counts, ell2, perm, out);
}

// Round 8
// 241.221 us; speedup vs baseline: 1.1607x; 1.1607x over previous
//
#include <hip/hip_runtime.h>

#define N_GENOMES 4000
#define N_SAMPLES 2048
#define N_GENES   28000
#define N_SEQS    16000
#define MAXW      16     // max genes per seq; P(exceed) ~1e-7 for Poisson(1.75) x 16000
#define SEQ_PER_BLOCK 4  // 1024-thread blocks, 256 threads per seq

// ---------------- ELL build: seq -> up to MAXW (genome, pos) pairs ----------------

__global__ void ell_scatter_k(const int* __restrict__ seq_idx,
                              const int* __restrict__ genome_idx,
                              const float* __restrict__ pos,
                              int* __restrict__ counts,
                              int2* __restrict__ ell2) {
    int g = blockIdx.x * blockDim.x + threadIdx.x;
    if (g < N_GENES) {
        int q = seq_idx[g];
        int slot = atomicAdd(&counts[q], 1);
        if (slot < MAXW)
            ell2[q * MAXW + slot] = make_int2(genome_idx[g], __float_as_int(pos[g]));
    }
}

// ---------------- main: 1024-thread block = 4 seq rows ----------------
// out[q, s] = bias[q] * sum_{g : seq_idx[g]==q} A[gi,s] * 2^(1 - pos[g]*B[gi,s])
// Fewer/bigger blocks: 4000 dispatches instead of 16000 -> CP dispatch rate
// no longer starves the CUs; 2 blocks/CU = 32 waves/CU (full).

__global__ __launch_bounds__(1024, 8) void main_ell_k(
    const float* __restrict__ A, const float* __restrict__ B,
    const float* __restrict__ bias,
    const int* __restrict__ counts, const int2* __restrict__ ell2,
    float* __restrict__ out)
{
    const int q   = blockIdx.x * SEQ_PER_BLOCK + (threadIdx.x >> 8);
    const int tid = threadIdx.x & 255;
    const int s0  = tid * 8;                    // 256 threads * 8 = 2048 samples

    int cnt = counts[q];
    if (cnt > MAXW) cnt = MAXW;
    const int2* row = ell2 + q * MAXW;

    // Unconditional metadata preload: always in-bounds, dead slots never consumed.
    int   gi[MAXW];
    float pp[MAXW];
#pragma unroll
    for (int j = 0; j < MAXW; ++j) {
        const int2 e = row[j];
        gi[j] = e.x;
        pp[j] = __int_as_float(e.y);
    }

    float acc[8];
#pragma unroll
    for (int i = 0; i < 8; ++i) acc[i] = 0.0f;

#pragma unroll
    for (int j = 0; j < MAXW; ++j) {
        if (j < cnt) {
            const float p = pp[j];
            const float4* Ar = (const float4*)(A + (size_t)gi[j] * N_SAMPLES + s0);
            const float4* Br = (const float4*)(B + (size_t)gi[j] * N_SAMPLES + s0);
            const float4 a0 = Ar[0], a1 = Ar[1];
            const float4 b0 = Br[0], b1 = Br[1];
            acc[0] += a0.x * exp2f(1.0f - p * b0.x);
            acc[1] += a0.y * exp2f(1.0f - p * b0.y);
            acc[2] += a0.z * exp2f(1.0f - p * b0.z);
            acc[3] += a0.w * exp2f(1.0f - p * b0.w);
            acc[4] += a1.x * exp2f(1.0f - p * b1.x);
            acc[5] += a1.y * exp2f(1.0f - p * b1.y);
            acc[6] += a1.z * exp2f(1.0f - p * b1.z);
            acc[7] += a1.w * exp2f(1.0f - p * b1.w);
        }
    }

    const float bq = bias[q];
    float4 o0 = make_float4(acc[0] * bq, acc[1] * bq, acc[2] * bq, acc[3] * bq);
    float4 o1 = make_float4(acc[4] * bq, acc[5] * bq, acc[6] * bq, acc[7] * bq);
    float4* Or = (float4*)(out + (size_t)q * N_SAMPLES + s0);
    Or[0] = o0;
    Or[1] = o1;
}

// ---------------- launch ----------------

extern "C" void kernel_launch(void* const* d_in, const int* in_sizes, int n_in,
                              void* d_out, int out_size, void* d_ws, size_t ws_size,
                              hipStream_t stream) {
    const float* A          = (const float*)d_in[0];   // (4000, 2048)
    const float* B          = (const float*)d_in[1];   // (4000, 2048)
    const float* bias       = (const float*)d_in[2];   // (16000,)
    const float* pos        = (const float*)d_in[3];   // (28000,)
    const int*   genome_idx = (const int*)d_in[4];     // (28000,)
    const int*   seq_idx    = (const int*)d_in[5];     // (28000,)
    float*       out        = (float*)d_out;           // (16000, 2048)

    int*  counts = (int*)d_ws;                          // 16000 ints
    int2* ell2   = (int2*)((char*)d_ws + ((N_SEQS * sizeof(int) + 15) & ~15));

    (void)hipMemsetAsync(counts, 0, N_SEQS * sizeof(int), stream);
    ell_scatter_k<<<(N_GENES + 255) / 256, 256, 0, stream>>>(seq_idx, genome_idx, pos,
                                                             counts, ell2);
    main_ell_k   <<<N_SEQS / SEQ_PER_BLOCK, 1024, 0, stream>>>(A, B, bias,
                                                               counts, ell2, out);
}